// Round 1
// baseline (167.965 us; speedup 1.0000x reference)
//
#include <hip/hip_runtime.h>
#include <hip/hip_bf16.h>
#include <stdint.h>

typedef __attribute__((ext_vector_type(8))) short short8;
typedef __bf16 bf16x8 __attribute__((ext_vector_type(8)));
typedef __attribute__((ext_vector_type(4))) float f32x4;

#define HID 128
#define NTILES 8   // 8 column tiles of 16 -> 128 hidden units
#define KSTEPS 4   // 4 K-steps of 32 -> K=128

__device__ __forceinline__ short f2bf(float x) {
    union { float f; uint32_t u; } v; v.f = x;
    uint32_t r = (v.u + 0x7FFFu + ((v.u >> 16) & 1u)) >> 16;
    return (short)r;
}

// ---------------- heads: l_high(4) | l_internal(5) | l_ext(30) -> out[0:39] (fp32 exact)
__global__ void heads_kernel(const float* __restrict__ node_hidden,
                             const float* __restrict__ h_glob,
                             const float* __restrict__ state,
                             const float* __restrict__ validity,
                             const float* __restrict__ W_hl1, const float* __restrict__ b_hl1,
                             const float* __restrict__ W_hl2, const float* __restrict__ b_hl2,
                             const float* __restrict__ W_in1, const float* __restrict__ b_in1,
                             const float* __restrict__ W_in2, const float* __restrict__ b_in2,
                             const float* __restrict__ W_ex1, const float* __restrict__ b_ex1,
                             const float* __restrict__ W_ex2, const float* __restrict__ b_ex2,
                             float* __restrict__ out)
{
    __shared__ float feats[264];
    __shared__ float hidden[3 * 128];
    const int tid = threadIdx.x;

    for (int i = tid; i < 264; i += 256) {
        float v;
        if (i < 128)      v = node_hidden[i];       // feats = [cur, h_glob, state]
        else if (i < 256) v = h_glob[i - 128];
        else              v = state[i - 256];
        feats[i] = v;
    }
    __syncthreads();

    for (int hid = tid; hid < 384; hid += 256) {
        const int head = hid >> 7, j = hid & 127;
        const float* W1 = (head == 0) ? W_hl1 : (head == 1 ? W_in1 : W_ex1);
        const float* b1 = (head == 0) ? b_hl1 : (head == 1 ? b_in1 : b_ex1);
        float h = b1[j];
        for (int i = 0; i < 264; ++i) h += feats[i] * W1[i * 128 + j];
        hidden[hid] = h > 0.f ? h : 0.f;
    }
    __syncthreads();

    if (tid < 39) {
        int head, col, od;
        const float *W2, *b2;
        if (tid < 4)      { head = 0; col = tid;     W2 = W_hl2; b2 = b_hl2; od = 4;  }
        else if (tid < 9) { head = 1; col = tid - 4; W2 = W_in2; b2 = b_in2; od = 5;  }
        else              { head = 2; col = tid - 9; W2 = W_ex2; b2 = b_ex2; od = 30; }
        float o = b2[col];
        const float* h = &hidden[head * 128];
        for (int i = 0; i < 128; ++i) o += h[i] * W2[i * od + col];
        if (head == 2) o += logf(validity[col]);
        out[tid] = o;
    }
}

// ---------------- teleport: per-node FFN, bf16 MFMA, fused epilogue -> out[39 + i]
__launch_bounds__(256, 4)
__global__ void teleport_kernel(const float* __restrict__ node_hidden, // n x 128
                                const float* __restrict__ h_glob,      // 128
                                const float* __restrict__ state,       // 8
                                const float* __restrict__ W1,          // 264 x 128 (W_tp1)
                                const float* __restrict__ b1,          // 128
                                const float* __restrict__ W2,          // 128 x 1
                                const float* __restrict__ b2,          // 1
                                float* __restrict__ out,               // pre-offset (+39)
                                int n)
{
    // B fragments: [tile t][kstep s][lane] -> 8 bf16 contiguous (16B, ds_read_b128)
    __shared__ __align__(16) short bfrag[NTILES * KSTEPS * 64 * 8];
    __shared__ float c_lds[HID];
    __shared__ float w2_lds[HID];

    const int tid = threadIdx.x;

    // Stage B = W1[128:256, :] as bf16 MFMA B-fragments.
    // B[k][col]: frag lane = (col&15) + 16*(k's 8-group), element j = k&7.
    for (int idx = tid; idx < HID * HID; idx += 256) {
        const int k = idx >> 7, nn = idx & 127;
        const int t = nn >> 4, cc = nn & 15;
        const int s = k >> 5, rr = k & 31;
        const int g = rr >> 3, j = rr & 7;
        const int lane = cc + (g << 4);
        bfrag[(((t * KSTEPS + s) * 64 + lane) << 3) + j] = f2bf(W1[(128 + k) * HID + nn]);
    }
    // Constant layer-1 offset: c = b1 + h_glob @ W1[0:128] + state @ W1[256:264]
    for (int j = tid; j < HID; j += 256) {
        float c = b1[j];
        for (int i = 0; i < 128; ++i) c += h_glob[i] * W1[i * HID + j];
        for (int i = 0; i < 8;  ++i) c += state[i] * W1[(256 + i) * HID + j];
        c_lds[j]  = c;
        w2_lds[j] = W2[j];
    }
    __syncthreads();

    const int lane = tid & 63;
    const int wave = tid >> 6;
    const int m = lane & 15;   // A row within tile / C col
    const int g = lane >> 4;   // k-group / C row-group
    const float bias2 = b2[0];

    float c_reg[NTILES], w2_reg[NTILES];
    #pragma unroll
    for (int t = 0; t < NTILES; ++t) {
        c_reg[t]  = c_lds[t * 16 + m];
        w2_reg[t] = w2_lds[t * 16 + m];
    }

    const int nChunks = (n + 15) >> 4;
    for (int chunk = blockIdx.x * 4 + wave; chunk < nChunks; chunk += gridDim.x * 4) {
        const int row0 = chunk << 4;
        const int arow = min(row0 + m, n - 1);
        const float4* Arow = (const float4*)(node_hidden + (size_t)arow * HID);

        f32x4 acc[NTILES];
        #pragma unroll
        for (int t = 0; t < NTILES; ++t) acc[t] = (f32x4){0.f, 0.f, 0.f, 0.f};

        #pragma unroll
        for (int s = 0; s < KSTEPS; ++s) {
            // lane needs A[row=m][k = s*32 + g*8 + j], j=0..7 -> two float4
            const float4 fa = Arow[s * 8 + g * 2];
            const float4 fb = Arow[s * 8 + g * 2 + 1];
            short8 af;
            af[0] = f2bf(fa.x); af[1] = f2bf(fa.y); af[2] = f2bf(fa.z); af[3] = f2bf(fa.w);
            af[4] = f2bf(fb.x); af[5] = f2bf(fb.y); af[6] = f2bf(fb.z); af[7] = f2bf(fb.w);
            const bf16x8 a = __builtin_bit_cast(bf16x8, af);
            #pragma unroll
            for (int t = 0; t < NTILES; ++t) {
                const short8 bs = *(const short8*)&bfrag[(((t * KSTEPS + s) * 64 + lane) << 3)];
                const bf16x8 b = __builtin_bit_cast(bf16x8, bs);
                acc[t] = __builtin_amdgcn_mfma_f32_16x16x32_bf16(a, b, acc[t], 0, 0, 0);
            }
        }

        // epilogue: h = relu(acc + c), dot with w2, reduce over the 16 cols
        float sr[4] = {0.f, 0.f, 0.f, 0.f};
        #pragma unroll
        for (int t = 0; t < NTILES; ++t) {
            #pragma unroll
            for (int r = 0; r < 4; ++r) {
                float h = acc[t][r] + c_reg[t];
                h = h > 0.f ? h : 0.f;
                sr[r] += h * w2_reg[t];
            }
        }
        #pragma unroll
        for (int d = 1; d < 16; d <<= 1) {
            #pragma unroll
            for (int r = 0; r < 4; ++r) sr[r] += __shfl_xor(sr[r], d, 64);
        }
        if (m == 0) {
            #pragma unroll
            for (int r = 0; r < 4; ++r) {
                const int orow = row0 + g * 4 + r;   // C row = g*4 + r
                if (orow < n) out[orow] = sr[r] + bias2;
            }
        }
    }
}

extern "C" void kernel_launch(void* const* d_in, const int* in_sizes, int n_in,
                              void* d_out, int out_size, void* d_ws, size_t ws_size,
                              hipStream_t stream) {
    const float* node_hidden = (const float*)d_in[0];
    const float* h_glob      = (const float*)d_in[1];
    const float* state       = (const float*)d_in[2];
    const float* validity    = (const float*)d_in[3];
    const float* W_hl1 = (const float*)d_in[4];  const float* b_hl1 = (const float*)d_in[5];
    const float* W_hl2 = (const float*)d_in[6];  const float* b_hl2 = (const float*)d_in[7];
    const float* W_in1 = (const float*)d_in[8];  const float* b_in1 = (const float*)d_in[9];
    const float* W_in2 = (const float*)d_in[10]; const float* b_in2 = (const float*)d_in[11];
    const float* W_ex1 = (const float*)d_in[12]; const float* b_ex1 = (const float*)d_in[13];
    const float* W_ex2 = (const float*)d_in[14]; const float* b_ex2 = (const float*)d_in[15];
    const float* W_tp1 = (const float*)d_in[16]; const float* b_tp1 = (const float*)d_in[17];
    const float* W_tp2 = (const float*)d_in[18]; const float* b_tp2 = (const float*)d_in[19];

    float* out = (float*)d_out;
    const int n = in_sizes[0] / HID;   // 400000

    heads_kernel<<<1, 256, 0, stream>>>(node_hidden, h_glob, state, validity,
                                        W_hl1, b_hl1, W_hl2, b_hl2,
                                        W_in1, b_in1, W_in2, b_in2,
                                        W_ex1, b_ex1, W_ex2, b_ex2,
                                        out);
    teleport_kernel<<<1024, 256, 0, stream>>>(node_hidden, h_glob, state,
                                              W_tp1, b_tp1, W_tp2, b_tp2,
                                              out + 39, n);
}

// Round 2
// 116.509 us; speedup vs baseline: 1.4416x; 1.4416x over previous
//
#include <hip/hip_runtime.h>
#include <hip/hip_bf16.h>
#include <stdint.h>

typedef __attribute__((ext_vector_type(8))) short short8;
typedef __bf16 bf16x8 __attribute__((ext_vector_type(8)));
typedef __attribute__((ext_vector_type(4))) float f32x4;

#define HID 128
#define NTILES 8   // 8 column tiles of 16 -> 128 hidden units
#define KSTEPS 4   // 4 K-steps of 32 -> K=128

// ws layout (as float index): [0,8192) bfrag (short[16384]); [8192,8320) c;
// [8320,8448) w2; [8448] b2.  Copied bytes: 33792 = 2112 * int4.
#define WS_C_F    8192
#define WS_W2_F   8320
#define WS_B2_F   8448

// ---------------- prep: heads (out[0:39], fp32 exact) + pack teleport weights into ws
__global__ void prep_kernel(const float* __restrict__ node_hidden,
                            const float* __restrict__ h_glob,
                            const float* __restrict__ state,
                            const float* __restrict__ validity,
                            const float* __restrict__ W_hl1, const float* __restrict__ b_hl1,
                            const float* __restrict__ W_hl2, const float* __restrict__ b_hl2,
                            const float* __restrict__ W_in1, const float* __restrict__ b_in1,
                            const float* __restrict__ W_in2, const float* __restrict__ b_in2,
                            const float* __restrict__ W_ex1, const float* __restrict__ b_ex1,
                            const float* __restrict__ W_ex2, const float* __restrict__ b_ex2,
                            const float* __restrict__ W_tp1, const float* __restrict__ b_tp1,
                            const float* __restrict__ W_tp2, const float* __restrict__ b_tp2,
                            float* __restrict__ out, float* __restrict__ ws)
{
    __shared__ float feats[264];
    __shared__ float hidden[3 * 128];
    const int tid = threadIdx.x;

    for (int i = tid; i < 264; i += 256) {
        float v;
        if (i < 128)      v = node_hidden[i];       // feats = [cur, h_glob, state]
        else if (i < 256) v = h_glob[i - 128];
        else              v = state[i - 256];
        feats[i] = v;
    }
    __syncthreads();

    for (int hid = tid; hid < 384; hid += 256) {
        const int head = hid >> 7, j = hid & 127;
        const float* W1 = (head == 0) ? W_hl1 : (head == 1 ? W_in1 : W_ex1);
        const float* b1 = (head == 0) ? b_hl1 : (head == 1 ? b_in1 : b_ex1);
        float h = b1[j];
        for (int i = 0; i < 264; ++i) h += feats[i] * W1[i * 128 + j];
        hidden[hid] = h > 0.f ? h : 0.f;
    }
    __syncthreads();

    if (tid < 39) {
        int head, col, od;
        const float *W2, *b2;
        if (tid < 4)      { head = 0; col = tid;     W2 = W_hl2; b2 = b_hl2; od = 4;  }
        else if (tid < 9) { head = 1; col = tid - 4; W2 = W_in2; b2 = b_in2; od = 5;  }
        else              { head = 2; col = tid - 9; W2 = W_ex2; b2 = b_ex2; od = 30; }
        float o = b2[col];
        const float* h = &hidden[head * 128];
        for (int i = 0; i < 128; ++i) o += h[i] * W2[i * od + col];
        if (head == 2) o += logf(validity[col]);
        out[tid] = o;
    }

    // ---- pack B = W_tp1[128:256,:] as bf16 MFMA B-fragments into ws
    short* bfrag = (short*)ws;
    for (int idx = tid; idx < HID * HID; idx += 256) {
        const int k = idx >> 7, nn = idx & 127;
        const int t = nn >> 4, cc = nn & 15;
        const int s = k >> 5, rr = k & 31;
        const int g = rr >> 3, j = rr & 7;
        const int lane = cc + (g << 4);
        bfrag[(((t * KSTEPS + s) * 64 + lane) << 3) + j] =
            (short)__builtin_bit_cast(unsigned short, (__bf16)W_tp1[(128 + k) * HID + nn]);
    }
    // ---- constant layer-1 offset: c = b1 + h_glob @ W1[0:128] + state @ W1[256:264]
    for (int j = tid; j < HID; j += 256) {
        float c = b_tp1[j];
        for (int i = 0; i < 128; ++i) c += h_glob[i] * W_tp1[i * HID + j];
        for (int i = 0; i < 8;  ++i)  c += state[i] * W_tp1[(256 + i) * HID + j];
        ws[WS_C_F + j]  = c;
        ws[WS_W2_F + j] = W_tp2[j];
    }
    if (tid == 0) ws[WS_B2_F] = b_tp2[0];
}

// ---------------- teleport: per-node FFN, bf16 MFMA, fused epilogue -> out[39 + i]
__launch_bounds__(512, 6)
__global__ void teleport_kernel(const float* __restrict__ node_hidden, // n x 128
                                const float* __restrict__ ws,          // packed weights
                                float* __restrict__ out,               // pre-offset (+39)
                                int n)
{
    __shared__ __align__(16) unsigned char smem[33792]; // bfrag 32KB | c 512B | w2 512B
    __shared__ __align__(16) float oscratch[8][16];

    const int tid = threadIdx.x;

    // coalesced ws -> LDS copy (2112 int4)
    {
        const int4* wsv = (const int4*)ws;
        int4* sv = (int4*)smem;
        for (int i = tid; i < 2112; i += 512) sv[i] = wsv[i];
    }
    const float bias2 = ws[WS_B2_F];
    __syncthreads();

    const short* bfrag  = (const short*)smem;
    const float* c_all  = (const float*)(smem + 32768);
    const float* w2_all = (const float*)(smem + 33280);

    const int lane = tid & 63;
    const int wave = tid >> 6;
    const int m = lane & 15;   // A row within tile / C col
    const int g = lane >> 4;   // k-group / C row-group

    float c_reg[NTILES], w2_reg[NTILES];
    #pragma unroll
    for (int t = 0; t < NTILES; ++t) {
        c_reg[t]  = c_all[t * 16 + m];
        w2_reg[t] = w2_all[t * 16 + m];
    }

    const int nChunks = (n + 15) >> 4;
    const int stride = gridDim.x * 8;
    for (int chunk = blockIdx.x * 8 + wave; chunk < nChunks; chunk += stride) {
        const int row0 = chunk << 4;
        const int arow = min(row0 + m, n - 1);
        const float4* Arow = (const float4*)(node_hidden + (size_t)arow * HID);

        f32x4 acc[NTILES];
        #pragma unroll
        for (int t = 0; t < NTILES; ++t) acc[t] = (f32x4){0.f, 0.f, 0.f, 0.f};

        #pragma unroll
        for (int s = 0; s < KSTEPS; ++s) {
            // lane needs A[row=m][k = s*32 + g*8 + j], j=0..7 -> contiguous 32B
            const float4 fa = Arow[s * 8 + g * 2];
            const float4 fb = Arow[s * 8 + g * 2 + 1];
            bf16x8 a;
            a[0] = (__bf16)fa.x; a[1] = (__bf16)fa.y; a[2] = (__bf16)fa.z; a[3] = (__bf16)fa.w;
            a[4] = (__bf16)fb.x; a[5] = (__bf16)fb.y; a[6] = (__bf16)fb.z; a[7] = (__bf16)fb.w;
            #pragma unroll
            for (int t = 0; t < NTILES; ++t) {
                const short8 bs = *(const short8*)&bfrag[(((t * KSTEPS + s) * 64 + lane) << 3)];
                const bf16x8 b = __builtin_bit_cast(bf16x8, bs);
                acc[t] = __builtin_amdgcn_mfma_f32_16x16x32_bf16(a, b, acc[t], 0, 0, 0);
            }
        }

        // epilogue: h = relu(acc + c), dot with w2, reduce over the 16 cols
        float sr[4] = {0.f, 0.f, 0.f, 0.f};
        #pragma unroll
        for (int t = 0; t < NTILES; ++t) {
            #pragma unroll
            for (int r = 0; r < 4; ++r) {
                float h = acc[t][r] + c_reg[t];
                h = h > 0.f ? h : 0.f;
                sr[r] += h * w2_reg[t];
            }
        }
        #pragma unroll
        for (int d = 1; d < 16; d <<= 1) {
            #pragma unroll
            for (int r = 0; r < 4; ++r) sr[r] += __shfl_xor(sr[r], d, 64);
        }
        // gather the wave's 16 results into lanes 0..15 via LDS, store 64B coalesced
        if (m == 0) {
            float4 v = make_float4(sr[0] + bias2, sr[1] + bias2, sr[2] + bias2, sr[3] + bias2);
            *(float4*)&oscratch[wave][g * 4] = v;   // C row = g*4 + r
        }
        asm volatile("s_waitcnt lgkmcnt(0)" ::: "memory");
        if (lane < 16) {
            const int orow = row0 + lane;
            if (orow < n) out[orow] = oscratch[wave][lane];
        }
    }
}

extern "C" void kernel_launch(void* const* d_in, const int* in_sizes, int n_in,
                              void* d_out, int out_size, void* d_ws, size_t ws_size,
                              hipStream_t stream) {
    const float* node_hidden = (const float*)d_in[0];
    const float* h_glob      = (const float*)d_in[1];
    const float* state       = (const float*)d_in[2];
    const float* validity    = (const float*)d_in[3];
    const float* W_hl1 = (const float*)d_in[4];  const float* b_hl1 = (const float*)d_in[5];
    const float* W_hl2 = (const float*)d_in[6];  const float* b_hl2 = (const float*)d_in[7];
    const float* W_in1 = (const float*)d_in[8];  const float* b_in1 = (const float*)d_in[9];
    const float* W_in2 = (const float*)d_in[10]; const float* b_in2 = (const float*)d_in[11];
    const float* W_ex1 = (const float*)d_in[12]; const float* b_ex1 = (const float*)d_in[13];
    const float* W_ex2 = (const float*)d_in[14]; const float* b_ex2 = (const float*)d_in[15];
    const float* W_tp1 = (const float*)d_in[16]; const float* b_tp1 = (const float*)d_in[17];
    const float* W_tp2 = (const float*)d_in[18]; const float* b_tp2 = (const float*)d_in[19];

    float* out = (float*)d_out;
    float* ws  = (float*)d_ws;
    const int n = in_sizes[0] / HID;   // 400000

    prep_kernel<<<1, 256, 0, stream>>>(node_hidden, h_glob, state, validity,
                                       W_hl1, b_hl1, W_hl2, b_hl2,
                                       W_in1, b_in1, W_in2, b_in2,
                                       W_ex1, b_ex1, W_ex2, b_ex2,
                                       W_tp1, b_tp1, W_tp2, b_tp2,
                                       out, ws);
    teleport_kernel<<<1024, 512, 0, stream>>>(node_hidden, ws, out + 39, n);
}